// Round 6
// baseline (55.583 us; speedup 1.0000x reference)
//
#include <hip/hip_runtime.h>
#include <stdint.h>

// Problem constants
#define B_  32
#define S_  512
#define C_  320
#define H_  512
#define NROW (B_*C_)          // 10240 GEMM N rows; N index n = b*320 + c (xws row)
                              // scrambled output row n' = c*32 + b

typedef __attribute__((ext_vector_type(8))) short short8;
typedef __attribute__((ext_vector_type(4))) float f32x4;

__device__ __forceinline__ unsigned short f2bf(float x){
  unsigned u = __builtin_bit_cast(unsigned, x);
  u = u + 0x7FFFu + ((u >> 16) & 1u);          // round-to-nearest-even
  return (unsigned short)(u >> 16);
}
__device__ __forceinline__ float bf2f(unsigned short h){
  unsigned u = ((unsigned)h) << 16;
  return __builtin_bit_cast(float, u);
}
__device__ __forceinline__ float sigf(float x){ return 1.0f/(1.0f + __expf(-x)); }
__device__ __forceinline__ float tanh_fast(float x){ return 2.0f/(1.0f + __expf(-2.0f*x)) - 1.0f; }

__device__ __forceinline__ void gload16(const void* g, void* l){
  __builtin_amdgcn_global_load_lds((const __attribute__((address_space(1))) void*)g,
                                   (__attribute__((address_space(3))) void*)l, 16, 0, 0);
}

// ---- Pass 0a: compact+cast w_ih rows {i:0-511, g:1024-1535, o:1536-2047}
//      -> aws[3][512][512] bf16 (f-gate dropped: c0 = 0 makes it dead) -------
__global__ __launch_bounds__(256) void k_cast_w(const float* __restrict__ w,
                                                unsigned short* __restrict__ aws){
  int flat = blockIdx.x*256 + threadIdx.x;     // float4 units; 3*512*512/4 = 196608
  int plane = flat >> 16;                       // 65536 float4 per 512x512 plane
  int rem   = flat & 65535;
  int srow  = (plane == 0 ? 0 : (plane == 1 ? 1024 : 1536));
  float4 v = ((const float4*)w)[srow*128 + rem];   // srow*512/4 + rem
  uint2 p;
  p.x = (unsigned)f2bf(v.x) | ((unsigned)f2bf(v.y) << 16);
  p.y = (unsigned)f2bf(v.z) | ((unsigned)f2bf(v.w) << 16);
  ((uint2*)aws)[flat] = p;
}

// ---- Pass 0b: x (b,s,c) f32 -> xws[b][c][s] bf16 (transpose) ---------------
__global__ __launch_bounds__(256) void k_cast_tx(const float* __restrict__ x,
                                                 unsigned short* __restrict__ xws){
  __shared__ float lds[64][65];
  const int tid = threadIdx.x;
  const int st = blockIdx.x, ctt = blockIdx.y, b = blockIdx.z;
  const int s0 = st*64, c0 = ctt*64;
  const int row = tid >> 2, q = tid & 3;

  const float* src = x + ((size_t)(b*S_ + s0 + row))*C_ + c0 + q*16;
  #pragma unroll
  for (int j = 0; j < 4; j++){
    float4 v = ((const float4*)src)[j];
    lds[row][q*16 + j*4 + 0] = v.x;
    lds[row][q*16 + j*4 + 1] = v.y;
    lds[row][q*16 + j*4 + 2] = v.z;
    lds[row][q*16 + j*4 + 3] = v.w;
  }
  __syncthreads();
  const int crow = row;
  #pragma unroll
  for (int j = 0; j < 2; j++){
    short8 o;
    #pragma unroll
    for (int e = 0; e < 8; e++)
      o[e] = (short)f2bf(lds[q*16 + j*8 + e][crow]);
    *(short8*)(xws + ((size_t)(b*C_ + c0 + crow))*S_ + s0 + q*16 + j*8) = o;
  }
}

// ---- Pass 1: MFMA GEMM + LSTM-cell epilogue --------------------------------
// GEMM: M=1536 (3 gates x 512 k), N=10240 (n = b*320+c = xws row), K=512.
// m97-style structure: BM=192 (3g x 64k) x BN=128 x BK=64, SINGLE-buffered
// 40 KB LDS, 256 threads = 4 waves (2M x 2N, 4 N-frags/wave),
// __launch_bounds__(256,3) -> 3 blocks/CU = 12 waves/CU; cross-block TLP
// hides the barrier drain (m114/m132).
// Grid 640 = 8 kt x 80 nt, XCD-chunked: fixed XCD walks kt 0..7 at constant
// nt -> B-slice 8x L2 reuse.
__global__ __launch_bounds__(256, 3) void k_gemm(const unsigned short* __restrict__ aws,
                                                 const unsigned short* __restrict__ xws,
                                                 const float* __restrict__ b_ih,
                                                 const float* __restrict__ b_hh,
                                                 unsigned short* __restrict__ hws){
  // A [3][64 krow][128B swz] at 0..24576; B [128 nrow][128B swz] at 24576..40960
  __shared__ alignas(16) char lds[40960];

  const int tid  = threadIdx.x;
  const int w    = tid >> 6;
  const int lane = tid & 63;
  const int wm = w >> 1, wn = w & 1;

  // decode: bid = n2*64 + kt*8 + x8; nt = n2*8 + x8
  const int bid = blockIdx.x;                  // 0..639
  const int x8 = bid & 7, y = bid >> 3;
  const int kt = y & 7, n2 = y >> 3;
  const int nt = n2*8 + x8;
  const int k0 = kt*64;
  const int nbase = nt*128;

  f32x4 acc[3][2][4];
  #pragma unroll
  for (int gi = 0; gi < 3; gi++)
    #pragma unroll
    for (int mf = 0; mf < 2; mf++)
      #pragma unroll
      for (int nf = 0; nf < 4; nf++)
        acc[gi][mf][nf] = (f32x4){0.f, 0.f, 0.f, 0.f};

  // staging: each global_load_lds = 1024B = 8 rows x 128B.
  // LDS slot (row, colb) holds global element (row, colb ^ ((row&7)<<4)).
  const int cr   = lane >> 3;
  const int slot = ((lane & 7) ^ cr) << 4;

  // 40 chunks (24 A + 16 B), 10 per wave; 32-bit offsets from ws base (=aws)
  const char* wsb = (const char*)aws;
  unsigned srcoff[10];
  int      dstoff[10];
  #pragma unroll
  for (int i = 0; i < 10; i++){
    int q = w*10 + i;
    if (q < 24){
      int gi = q >> 3, q8 = q & 7;
      int grow = gi*512 + k0 + q8*8 + cr;
      srcoff[i] = (unsigned)(grow*1024 + slot);              // aws at ws+0, row stride 1024B
      dstoff[i] = gi*8192 + q8*1024;
    } else {
      int q8 = q - 24;                                       // 0..15
      int xrow = nbase + q8*8 + cr;                          // xws row == GEMM n
      srcoff[i] = (unsigned)(2097152 + xrow*1024 + slot);    // xws at ws+2MiB
      dstoff[i] = 24576 + q8*1024;
    }
  }

  const int lo16 = (lane >> 4) << 4;
  const int swz  = (lane & 7) << 4;
  const int l15  = lane & 15;

  for (int t = 0; t < 8; t++){
    #pragma unroll
    for (int i = 0; i < 10; i++){
      gload16(wsb + (size_t)srcoff[i], &lds[0] + dstoff[i]);
      srcoff[i] += 128;
    }
    __syncthreads();                           // stage t complete (vmcnt drain)
    #pragma unroll
    for (int ks = 0; ks < 2; ks++){
      const int colb = (ks*64 + lo16) ^ swz;
      short8 aF[3][2], bF[4];
      #pragma unroll
      for (int gi = 0; gi < 3; gi++)
        #pragma unroll
        for (int mf = 0; mf < 2; mf++)
          aF[gi][mf] = *(const short8*)(&lds[0] + gi*8192 + (wm*32 + mf*16 + l15)*128 + colb);
      #pragma unroll
      for (int nf = 0; nf < 4; nf++)
        bF[nf] = *(const short8*)(&lds[0] + 24576 + (wn*64 + nf*16 + l15)*128 + colb);
      #pragma unroll
      for (int gi = 0; gi < 3; gi++)
        #pragma unroll
        for (int mf = 0; mf < 2; mf++)
          #pragma unroll
          for (int nf = 0; nf < 4; nf++)
            acc[gi][mf][nf] = __builtin_amdgcn_mfma_f32_16x16x32_bf16(aF[gi][mf], bF[nf], acc[gi][mf][nf], 0, 0, 0);
    }
    __syncthreads();                           // reads done before next stage
  }

  // epilogue: gate-combine -> h, write bf16 hws[n'][k], n' = c*32 + b.
  // Lane quads share n' and fill 16 contiguous k (32B) per (mf,nf) store.
  #pragma unroll
  for (int mf = 0; mf < 2; mf++){
    const int kb = k0 + wm*32 + mf*16 + ((lane >> 4) << 2);   // + r
    float bi[4], bg[4], bo[4];
    #pragma unroll
    for (int r = 0; r < 4; r++){
      bi[r] = b_ih[kb + r]        + b_hh[kb + r];
      bg[r] = b_ih[1024 + kb + r] + b_hh[1024 + kb + r];
      bo[r] = b_ih[1536 + kb + r] + b_hh[1536 + kb + r];
    }
    #pragma unroll
    for (int nf = 0; nf < 4; nf++){
      const int n = nbase + wn*64 + nf*16 + l15;   // = b*320 + c
      const int bb = n / 320;                      // const-div -> magic mul
      const int cc = n - bb*320;
      const size_t nr = (size_t)cc*32 + (size_t)bb;
      float h[4];
      #pragma unroll
      for (int r = 0; r < 4; r++){
        float iv = acc[0][mf][nf][r] + bi[r];
        float gv = acc[1][mf][nf][r] + bg[r];
        float ov = acc[2][mf][nf][r] + bo[r];
        float ce = sigf(iv) * tanh_fast(gv);
        h[r] = sigf(ov) * tanh_fast(ce);
      }
      uint2 p2;
      p2.x = (unsigned)f2bf(h[0]) | ((unsigned)f2bf(h[1]) << 16);
      p2.y = (unsigned)f2bf(h[2]) | ((unsigned)f2bf(h[3]) << 16);
      *(uint2*)(hws + nr*H_ + kb) = p2;
    }
  }
}

// ---- Pass 2: out[b2,k,c2] = f32(hws[b2*320+c2][k]) — LDS transpose ---------
__global__ __launch_bounds__(256) void k_out(const unsigned short* __restrict__ hws,
                                             float* __restrict__ out){
  __shared__ float lds[64][65];
  const int tid = threadIdx.x;
  const int kt = blockIdx.x, ctt = blockIdx.y, b2 = blockIdx.z;
  const int k0 = kt*64, n0 = b2*320 + ctt*64;
  const int rr = tid >> 2, q = tid & 3;

  #pragma unroll
  for (int j = 0; j < 2; j++){
    short8 v = *(const short8*)(hws + ((size_t)(n0 + rr))*H_ + k0 + q*16 + j*8);
    #pragma unroll
    for (int e = 0; e < 8; e++)
      lds[rr][q*16 + j*8 + e] = bf2f((unsigned short)v[e]);
  }
  __syncthreads();
  const int krow = rr;
  #pragma unroll
  for (int j = 0; j < 4; j++){
    int c2l = q*16 + j*4;
    float4 o;
    o.x = lds[c2l + 0][krow];
    o.y = lds[c2l + 1][krow];
    o.z = lds[c2l + 2][krow];
    o.w = lds[c2l + 3][krow];
    *(float4*)(out + (size_t)b2*(H_*C_) + (size_t)(k0 + krow)*C_ + ctt*64 + c2l) = o;
  }
}

extern "C" void kernel_launch(void* const* d_in, const int* in_sizes, int n_in,
                              void* d_out, int out_size, void* d_ws, size_t ws_size,
                              hipStream_t stream){
  const float* x    = (const float*)d_in[0];
  const float* w_ih = (const float*)d_in[1];
  // d_in[2] = w_hh is mathematically dead (h0 = 0)
  const float* b_ih = (const float*)d_in[3];
  const float* b_hh = (const float*)d_in[4];
  float* out = (float*)d_out;

  char* ws = (char*)d_ws;
  unsigned short* aws = (unsigned short*)(ws);                           // 1.5 MiB (3*512*512 bf16)
  unsigned short* xws = (unsigned short*)(ws + 2097152);                 // 10 MiB  (10240*512 bf16)
  unsigned short* hws = (unsigned short*)(ws + 2097152 + 10485760);      // 10 MiB  (10240*512 bf16)
  // total workspace use: ~22 MiB

  k_cast_w <<<768, 256, 0, stream>>>(w_ih, aws);
  k_cast_tx<<<dim3(8, 5, 32), 256, 0, stream>>>(x, xws);
  k_gemm   <<<640, 256, 0, stream>>>(aws, xws, b_ih, b_hh, hws);
  k_out    <<<dim3(8, 5, 32), 256, 0, stream>>>(hws, out);
}

// Round 7
// 53.193 us; speedup vs baseline: 1.0449x; 1.0449x over previous
//
#include <hip/hip_runtime.h>
#include <stdint.h>

// Problem constants
#define B_  32
#define S_  512
#define C_  320
#define H_  512
#define NROW (B_*C_)          // 10240 rows; scrambled output row n' = c*32 + b

typedef __attribute__((ext_vector_type(8))) short short8;
typedef __attribute__((ext_vector_type(4))) float f32x4;

__device__ __forceinline__ unsigned short f2bf(float x){
  unsigned u = __builtin_bit_cast(unsigned, x);
  u = u + 0x7FFFu + ((u >> 16) & 1u);          // round-to-nearest-even
  return (unsigned short)(u >> 16);
}
__device__ __forceinline__ float bf2f(unsigned short h){
  unsigned u = ((unsigned)h) << 16;
  return __builtin_bit_cast(float, u);
}
__device__ __forceinline__ float sigf(float x){ return 1.0f/(1.0f + __expf(-x)); }
__device__ __forceinline__ float tanh_fast(float x){ return 2.0f/(1.0f + __expf(-2.0f*x)) - 1.0f; }

__device__ __forceinline__ void gload16(const void* g, void* l){
  __builtin_amdgcn_global_load_lds((const __attribute__((address_space(1))) void*)g,
                                   (__attribute__((address_space(3))) void*)l, 16, 0, 0);
}

// ---- Pass 0a: compact+cast w_ih rows {i:0-511, g:1024-1535, o:1536-2047}
//      -> aws[3][512][512] bf16 (f-gate dropped: c0 = 0 makes it dead) -------
__global__ __launch_bounds__(256) void k_cast_w(const float* __restrict__ w,
                                                unsigned short* __restrict__ aws){
  int flat = blockIdx.x*256 + threadIdx.x;     // float4 units; 3*512*512/4 = 196608
  int plane = flat >> 16;                       // 65536 float4 per 512x512 plane
  int rem   = flat & 65535;
  int srow  = (plane == 0 ? 0 : (plane == 1 ? 1024 : 1536));
  float4 v = ((const float4*)w)[srow*128 + rem];   // srow*512/4 + rem
  uint2 p;
  p.x = (unsigned)f2bf(v.x) | ((unsigned)f2bf(v.y) << 16);
  p.y = (unsigned)f2bf(v.z) | ((unsigned)f2bf(v.w) << 16);
  ((uint2*)aws)[flat] = p;
}

// ---- Pass 0b: x (b,s,c) f32 -> xws[b][c][s] bf16 (transpose) ---------------
__global__ __launch_bounds__(256) void k_cast_tx(const float* __restrict__ x,
                                                 unsigned short* __restrict__ xws){
  __shared__ float lds[64][65];
  const int tid = threadIdx.x;
  const int st = blockIdx.x, ctt = blockIdx.y, b = blockIdx.z;
  const int s0 = st*64, c0 = ctt*64;
  const int row = tid >> 2, q = tid & 3;

  const float* src = x + ((size_t)(b*S_ + s0 + row))*C_ + c0 + q*16;
  #pragma unroll
  for (int j = 0; j < 4; j++){
    float4 v = ((const float4*)src)[j];
    lds[row][q*16 + j*4 + 0] = v.x;
    lds[row][q*16 + j*4 + 1] = v.y;
    lds[row][q*16 + j*4 + 2] = v.z;
    lds[row][q*16 + j*4 + 3] = v.w;
  }
  __syncthreads();
  const int crow = row;
  #pragma unroll
  for (int j = 0; j < 2; j++){
    short8 o;
    #pragma unroll
    for (int e = 0; e < 8; e++)
      o[e] = (short)f2bf(lds[q*16 + j*8 + e][crow]);
    *(short8*)(xws + ((size_t)(b*C_ + c0 + crow))*S_ + s0 + q*16 + j*8) = o;
  }
}

// ---- Pass 1: MFMA GEMM + LSTM-cell epilogue --------------------------------
// GEMM: M=1536 (3 gates x 512 k), N=10240, K=512.
// Tile BM=192 (3g x 64k) x BN=320 (one full b) x BK=64; 512 thr = 8 waves
// (2M x 4N); grid 256 = 8 kt x 32 b = 1 block/CU, single residency round.
// Counted-vmcnt double-buffered pipeline (T3/T4): per K-step
//   22 ds_read -> lgkmcnt(0) -> s_barrier -> issue 8 gload(t+2 into buf[p])
//   -> 60 MFMA -> vmcnt(8) (t+1 landed, t+2 in flight) -> s_barrier.
// vmcnt never drains to 0 in steady state; loads stay in flight across
// barriers (the m218 lever; __syncthreads' vmcnt(0) drain was the 46us stall).
__global__ __launch_bounds__(512, 2) void k_gemm(const unsigned short* __restrict__ aws,
                                                 const unsigned short* __restrict__ xws,
                                                 const float* __restrict__ b_ih,
                                                 const float* __restrict__ b_hh,
                                                 unsigned short* __restrict__ hws){
  // per-parity: A [3][64 krow][128B swz] at 0..24576; B [320 nrow][128B swz]
  // at 24576..65536. Parity stride 65536.
  __shared__ alignas(16) char lds[2][65536];

  const int tid  = threadIdx.x;
  const int w    = tid >> 6;
  const int lane = tid & 63;
  const int wm = w >> 2, wn = w & 3;

  // XCD decode: b % 8 == xcd; 8 kt-blocks of one b share an XCD (B-slice L2 reuse)
  const int bid = blockIdx.x;                  // 0..255
  const int xcd = bid & 7, j = bid >> 3;
  const int b  = ((j >> 3) << 3) + xcd;        // 0..31
  const int kt = j & 7;
  const int k0 = kt*64;

  f32x4 acc[3][2][5];
  #pragma unroll
  for (int gi = 0; gi < 3; gi++)
    #pragma unroll
    for (int mf = 0; mf < 2; mf++)
      #pragma unroll
      for (int nf = 0; nf < 5; nf++)
        acc[gi][mf][nf] = (f32x4){0.f, 0.f, 0.f, 0.f};

  // staging: each global_load_lds = 1024B = 8 rows x 128B.
  // LDS slot (row, colb) holds global element (row, colb ^ ((row&7)<<4)).
  const int cr   = lane >> 3;
  const int slot = ((lane & 7) ^ cr) << 4;

  // 64 chunks (24 A + 40 B), 8 per wave; 32-bit offsets from ws base (=aws)
  const char* wsb = (const char*)aws;
  unsigned srcoff[8];
  int      dstoff[8];
  #pragma unroll
  for (int i = 0; i < 8; i++){
    int q = w*8 + i;
    if (q < 24){
      int gi = q >> 3, q8 = q & 7;
      int grow = gi*512 + k0 + q8*8 + cr;
      srcoff[i] = (unsigned)(grow*1024 + slot);              // aws at ws+0
      dstoff[i] = gi*8192 + q8*1024;
    } else {
      int q8 = q - 24;                                       // 0..39
      int xrow = b*C_ + q8*8 + cr;
      srcoff[i] = (unsigned)(2097152 + xrow*1024 + slot);    // xws at ws+2MiB
      dstoff[i] = 24576 + q8*1024;
    }
  }

  // prologue: tile 0 -> buf0, tile 1 -> buf1; wait tile 0 (8 newest = tile 1)
  #pragma unroll
  for (int i = 0; i < 8; i++) gload16(wsb + (size_t)srcoff[i],       &lds[0][0] + dstoff[i]);
  #pragma unroll
  for (int i = 0; i < 8; i++) gload16(wsb + (size_t)(srcoff[i]+128), &lds[0][0] + dstoff[i] + 65536);
  asm volatile("s_waitcnt vmcnt(8)" ::: "memory");
  __builtin_amdgcn_sched_barrier(0);
  __builtin_amdgcn_s_barrier();

  const int lo16 = (lane >> 4) << 4;
  const int swz  = (lane & 7) << 4;
  const int l15  = lane & 15;
  const int arow0 = (wm*32 + l15)*128;         // + mf*16*128
  const int brow0 = (wn*80 + l15)*128;         // + nf*16*128

  #pragma unroll
  for (int t = 0; t < 8; t++){
    const int p = t & 1;
    char* base = &lds[0][0] + (p << 16);

    // ---- read ALL fragments for this tile (both K-halves) ----
    short8 aF[2][3][2], bF[2][5];
    #pragma unroll
    for (int ks = 0; ks < 2; ks++){
      const int colb = (ks*64 + lo16) ^ swz;
      #pragma unroll
      for (int gi = 0; gi < 3; gi++)
        #pragma unroll
        for (int mf = 0; mf < 2; mf++)
          aF[ks][gi][mf] = *(const short8*)(base + gi*8192 + arow0 + mf*2048 + colb);
      #pragma unroll
      for (int nf = 0; nf < 5; nf++)
        bF[ks][nf] = *(const short8*)(base + 24576 + brow0 + nf*2048 + colb);
    }
    asm volatile("s_waitcnt lgkmcnt(0)" ::: "memory");
    __builtin_amdgcn_sched_barrier(0);
    __builtin_amdgcn_s_barrier();              // all waves done reading buf[p]

    // ---- issue stage of tile t+2 into buf[p] (overwrites what we just read)
    if (t < 6){
      #pragma unroll
      for (int i = 0; i < 8; i++)
        gload16(wsb + (size_t)(srcoff[i] + (unsigned)(t+2)*128), base + dstoff[i]);
      __builtin_amdgcn_sched_barrier(0);       // keep stage-issue ahead of MFMA
    }

    // ---- 60 MFMA on registers (covers tile t+1's in-flight latency) ----
    #pragma unroll
    for (int ks = 0; ks < 2; ks++)
      #pragma unroll
      for (int gi = 0; gi < 3; gi++)
        #pragma unroll
        for (int mf = 0; mf < 2; mf++)
          #pragma unroll
          for (int nf = 0; nf < 5; nf++)
            acc[gi][mf][nf] = __builtin_amdgcn_mfma_f32_16x16x32_bf16(aF[ks][gi][mf], bF[ks][nf], acc[gi][mf][nf], 0, 0, 0);

    // ---- counted wait: tile t+1 complete (tile t+2 still in flight) ----
    if (t < 7){
      if (t < 6){ asm volatile("s_waitcnt vmcnt(8)" ::: "memory"); }
      else      { asm volatile("s_waitcnt vmcnt(0)" ::: "memory"); }
      __builtin_amdgcn_sched_barrier(0);
      __builtin_amdgcn_s_barrier();            // buf[p^1] ready for next iter
    }
  }

  // epilogue: gate-combine -> h, write bf16 hws[n'][k], n' = c*32 + b.
  #pragma unroll
  for (int mf = 0; mf < 2; mf++){
    const int kb = k0 + wm*32 + mf*16 + ((lane >> 4) << 2);   // + r
    float bi[4], bg[4], bo[4];
    #pragma unroll
    for (int r = 0; r < 4; r++){
      bi[r] = b_ih[kb + r]        + b_hh[kb + r];
      bg[r] = b_ih[1024 + kb + r] + b_hh[1024 + kb + r];
      bo[r] = b_ih[1536 + kb + r] + b_hh[1536 + kb + r];
    }
    #pragma unroll
    for (int nf = 0; nf < 5; nf++){
      const int c = wn*80 + nf*16 + l15;             // 0..319 (full b in-block)
      const size_t nr = (size_t)c*32 + (size_t)b;    // the scramble: c*B + b
      float h[4];
      #pragma unroll
      for (int r = 0; r < 4; r++){
        float iv = acc[0][mf][nf][r] + bi[r];
        float gv = acc[1][mf][nf][r] + bg[r];
        float ov = acc[2][mf][nf][r] + bo[r];
        float ce = sigf(iv) * tanh_fast(gv);
        h[r] = sigf(ov) * tanh_fast(ce);
      }
      uint2 p2;
      p2.x = (unsigned)f2bf(h[0]) | ((unsigned)f2bf(h[1]) << 16);
      p2.y = (unsigned)f2bf(h[2]) | ((unsigned)f2bf(h[3]) << 16);
      *(uint2*)(hws + nr*H_ + kb) = p2;
    }
  }
}

// ---- Pass 2: out[b2,k,c2] = f32(hws[b2*320+c2][k]) — LDS transpose ---------
__global__ __launch_bounds__(256) void k_out(const unsigned short* __restrict__ hws,
                                             float* __restrict__ out){
  __shared__ float lds[64][65];
  const int tid = threadIdx.x;
  const int kt = blockIdx.x, ctt = blockIdx.y, b2 = blockIdx.z;
  const int k0 = kt*64, n0 = b2*320 + ctt*64;
  const int rr = tid >> 2, q = tid & 3;

  #pragma unroll
  for (int j = 0; j < 2; j++){
    short8 v = *(const short8*)(hws + ((size_t)(n0 + rr))*H_ + k0 + q*16 + j*8);
    #pragma unroll
    for (int e = 0; e < 8; e++)
      lds[rr][q*16 + j*8 + e] = bf2f((unsigned short)v[e]);
  }
  __syncthreads();
  const int krow = rr;
  #pragma unroll
  for (int j = 0; j < 4; j++){
    int c2l = q*16 + j*4;
    float4 o;
    o.x = lds[c2l + 0][krow];
    o.y = lds[c2l + 1][krow];
    o.z = lds[c2l + 2][krow];
    o.w = lds[c2l + 3][krow];
    *(float4*)(out + (size_t)b2*(H_*C_) + (size_t)(k0 + krow)*C_ + ctt*64 + c2l) = o;
  }
}

extern "C" void kernel_launch(void* const* d_in, const int* in_sizes, int n_in,
                              void* d_out, int out_size, void* d_ws, size_t ws_size,
                              hipStream_t stream){
  const float* x    = (const float*)d_in[0];
  const float* w_ih = (const float*)d_in[1];
  // d_in[2] = w_hh is mathematically dead (h0 = 0)
  const float* b_ih = (const float*)d_in[3];
  const float* b_hh = (const float*)d_in[4];
  float* out = (float*)d_out;

  char* ws = (char*)d_ws;
  unsigned short* aws = (unsigned short*)(ws);                           // 1.5 MiB (3*512*512 bf16)
  unsigned short* xws = (unsigned short*)(ws + 2097152);                 // 10 MiB  (10240*512 bf16)
  unsigned short* hws = (unsigned short*)(ws + 2097152 + 10485760);      // 10 MiB  (10240*512 bf16)
  // total workspace use: ~22 MiB

  k_cast_w <<<768, 256, 0, stream>>>(w_ih, aws);
  k_cast_tx<<<dim3(8, 5, 32), 256, 0, stream>>>(x, xws);
  k_gemm   <<<256, 512, 0, stream>>>(aws, xws, b_ih, b_hh, hws);
  k_out    <<<dim3(8, 5, 32), 256, 0, stream>>>(hws, out);
}